// Round 4
// baseline (12590.871 us; speedup 1.0000x reference)
//
#include <hip/hip_runtime.h>
#include <hip/hip_cooperative_groups.h>
#include <cstddef>

namespace cg = cooperative_groups;

typedef unsigned short ushort_t;
typedef __attribute__((ext_vector_type(8))) short bhalf8;
typedef __attribute__((ext_vector_type(4))) unsigned short ushort4v;
typedef __attribute__((ext_vector_type(4))) float floatx4;

#define T_STEPS 63

__device__ __forceinline__ float bf2f(unsigned short u) {
  union { unsigned int i; float f; } c; c.i = ((unsigned int)u) << 16; return c.f;
}
__device__ __forceinline__ unsigned short f2bf(float f) {
  union { float f; unsigned int i; } c; c.f = f;
  unsigned int x = c.i;
  return (unsigned short)((x + 0x7FFFu + ((x >> 16) & 1u)) >> 16);
}
__device__ __forceinline__ float tanh_f(float x) {
  float e = exp2f(x * 2.8853900817779268f);
  return 1.f - 2.f / (e + 1.f);
}
__device__ __forceinline__ float sigm_f(float x) {
  return 1.f / (1.f + exp2f(x * -1.4426950408889634f));
}

// ---------------------------------------------------------------------------
// Multi-segment fp32 -> bf16 conversion (up to 5 independent segments, quads).
__global__ __launch_bounds__(256) void conv5_k(
    const float* __restrict__ s0, ushort_t* __restrict__ d0, int n0,
    const float* __restrict__ s1, ushort_t* __restrict__ d1, int n1,
    const float* __restrict__ s2, ushort_t* __restrict__ d2, int n2,
    const float* __restrict__ s3, ushort_t* __restrict__ d3, int n3,
    const float* __restrict__ s4, ushort_t* __restrict__ d4, int n4) {
  int g = blockIdx.x * 256 + threadIdx.x;
  const float* s; ushort_t* d; int off;
  int e0 = n0, e1 = e0 + n1, e2 = e1 + n2, e3 = e2 + n3, e4 = e3 + n4;
  if      (g < e0) { s = s0; d = d0; off = g; }
  else if (g < e1) { s = s1; d = d1; off = g - e0; }
  else if (g < e2) { s = s2; d = d2; off = g - e1; }
  else if (g < e3) { s = s3; d = d3; off = g - e2; }
  else if (g < e4) { s = s4; d = d4; off = g - e3; }
  else return;
  floatx4 v = ((const floatx4*)s)[off];
  ushort4v o;
  o[0] = f2bf(v[0]); o[1] = f2bf(v[1]); o[2] = f2bf(v[2]); o[3] = f2bf(v[3]);
  ((ushort4v*)d)[off] = o;
}

// ---------------------------------------------------------------------------
// bsum[i] = b_in[i] + b_ctx[i] (f32); vattbf[i] = bf16(v_att[i]).
__global__ __launch_bounds__(256) void bsum_k(const float* __restrict__ b_in,
    const float* __restrict__ b_ctx, const float* __restrict__ v_att,
    float* __restrict__ bsum, ushort_t* __restrict__ vattbf) {
  int i = blockIdx.x * 256 + threadIdx.x;
  if (i < 1024) {
    bsum[i] = b_in[i] + b_ctx[i];
    vattbf[i] = f2bf(v_att[i]);
  }
}

// ---------------------------------------------------------------------------
// init h1/h2 (fp32 + bf16 mirror) from dec_init (NL,N,H) fp32. 65536 threads.
__global__ __launch_bounds__(256) void init_k(const float* __restrict__ dec_init,
    float* __restrict__ h1, float* __restrict__ h2,
    ushort_t* __restrict__ h1bf, ushort_t* __restrict__ h2bf) {
  int g = blockIdx.x * 256 + threadIdx.x;
  int l = g >> 15, idx = g & 32767;
  float f = dec_init[g];
  if (l == 0) { h1[idx] = f; h1bf[idx] = f2bf(f); }
  else        { h2[idx] = f; h2bf[idx] = f2bf(f); }
}

// ---------------------------------------------------------------------------
// Gather decoder-input embedding rows to bf16, padded to 2048 rows with zeros.
// row = t*32 + n ; X[row] = bf16(emb_table[ids[n,t]]). Grid 2048 x 256.
__global__ __launch_bounds__(256) void gather_emb_k(const int* __restrict__ ids,
    const float* __restrict__ emb_table, ushort_t* __restrict__ Xg) {
  int g = blockIdx.x * 256 + threadIdx.x;   // 524288 quads
  int row = g >> 8, q = g & 255;
  ushort4v o;
  if (row < 2016) {
    int tt = row >> 5, n = row & 31;
    int eid = ids[n * 64 + tt];
    floatx4 v = *(const floatx4*)(emb_table + (size_t)eid * 1024 + q * 4);
    o[0] = f2bf(v[0]); o[1] = f2bf(v[1]); o[2] = f2bf(v[2]); o[3] = f2bf(v[3]);
  } else {
    o[0] = 0; o[1] = 0; o[2] = 0; o[3] = 0;
  }
  ((ushort4v*)Xg)[g] = o;
}

// ---------------------------------------------------------------------------
// Shared 32-row x 32-col x K=1024 bf16 MFMA tile (verified stage0 structure).
// Xs: 32 rows stride 1024; Wp: 32 rows (output cols) stride 1024.
// Returns this thread's 16x16-fragment accumulator (wave-tiled 2x2).
__device__ __forceinline__ floatx4 tile_gemm32(
    const ushort_t* __restrict__ Xs, const ushort_t* __restrict__ Wp,
    ushort_t* sXk, ushort_t* sBk, int tid) {
  int wid = tid >> 6, lane = tid & 63;
  int klane = (lane >> 4) << 3;
  int nt = wid & 1, mt = wid >> 1;
  floatx4 acc = {0, 0, 0, 0};
  for (int kp = 0; kp < 4; ++kp) {
    __syncthreads();
    #pragma unroll
    for (int it = 0; it < 4; ++it) {
      int v = it * 256 + tid; int row = v >> 5, vc = v & 31;
      *(bhalf8*)(&sXk[row * 264 + vc * 8]) = *(const bhalf8*)(Xs + (size_t)row * 1024 + kp * 256 + vc * 8);
      *(bhalf8*)(&sBk[row * 264 + vc * 8]) = *(const bhalf8*)(Wp + (size_t)(row)*1024 + kp * 256 + vc * 8);
    }
    __syncthreads();
    #pragma unroll
    for (int kit = 0; kit < 8; ++kit) {
      int k = kit * 32 + klane;
      bhalf8 a  = *(const bhalf8*)(&sXk[(mt * 16 + (lane & 15)) * 264 + k]);
      bhalf8 bf = *(const bhalf8*)(&sBk[(nt * 16 + (lane & 15)) * 264 + k]);
      acc = __builtin_amdgcn_mfma_f32_16x16x32_bf16(a, bf, acc, 0, 0, 0);
    }
  }
  return acc;
}

// ---------------------------------------------------------------------------
// Precompute GEMM body: out[row,c] = bf16( X[row,:] . W[c,:] + bias[c] ), K=1024.
// b encodes rowblock<<5 | colblock; stores guarded by row < R.
__device__ __forceinline__ void gemm_pre_body(int b, int tid,
    const ushort_t* __restrict__ Xbf, const ushort_t* __restrict__ Wbf,
    const float* __restrict__ bias, ushort_t* __restrict__ outp, int R,
    ushort_t* sXk, ushort_t* sBk) {
  int rb = b >> 5, cb = b & 31;
  int r0 = rb << 5, c0 = cb << 5;
  floatx4 acc = tile_gemm32(Xbf + (size_t)r0 * 1024, Wbf + (size_t)c0 * 1024, sXk, sBk, tid);
  int wid = tid >> 6, lane = tid & 63;
  int nt = wid & 1, mt = wid >> 1;
  int colw = c0 + nt * 16 + (lane & 15);
  float bv = bias ? bias[colw] : 0.f;
  int rl = (lane >> 4) << 2;
  #pragma unroll
  for (int i = 0; i < 4; ++i) {
    int row = r0 + mt * 16 + rl + i;
    if (row < R) outp[(size_t)row * 1024 + colw] = f2bf(acc[i] + bv);
  }
}

// Fused dual precompute GEMM: b<2048 -> encp (2048 rows, no bias);
// b>=2048 -> membp (2016 rows, bias=bsum). Grid 4096 x 256.
__global__ __launch_bounds__(256) void gemm_pre2_k(
    const ushort_t* __restrict__ encX, const ushort_t* __restrict__ Wae,
    const ushort_t* __restrict__ membX, const ushort_t* __restrict__ Win,
    const float* __restrict__ bsum,
    ushort_t* __restrict__ encp, ushort_t* __restrict__ membp) {
  __shared__ __align__(16) ushort_t sXk[32 * 264];
  __shared__ __align__(16) ushort_t sBk[32 * 264];
  int b = blockIdx.x, tid = threadIdx.x;
  if (b < 2048)
    gemm_pre_body(b, tid, encX, Wae, (const float*)nullptr, encp, 2048, sXk, sBk);
  else
    gemm_pre_body(b - 2048, tid, membX, Win, bsum, membp, 2016, sXk, sBk);
}

// ---------------------------------------------------------------------------
// Fused attention body (verbatim math from verified att_k).
__device__ __forceinline__ void att_body(int t, int n, int tid,
    const ushort_t* __restrict__ encp, const float* __restrict__ dprj,
    const ushort_t* __restrict__ vattbf, const float* __restrict__ enc_hids,
    ushort_t* __restrict__ ctxbf, float* __restrict__ out_att,
    float* sSc, float* sAtt) {
  int l = tid >> 2, q = tid & 3;
  const ushort_t* ep = encp + ((size_t)(n * 64 + l)) * 1024 + q * 256;
  const float*    dp = dprj + n * 1024 + q * 256;
  float p = 0.f;
  for (int it = 0; it < 32; ++it) {
    bhalf8 E = *(const bhalf8*)(ep + it * 8);
    bhalf8 V = *(const bhalf8*)(vattbf + q * 256 + it * 8);
    #pragma unroll
    for (int r = 0; r < 8; ++r)
      p += tanh_f(bf2f((unsigned short)E[r]) + dp[it * 8 + r]) * bf2f((unsigned short)V[r]);
  }
  p += __shfl_down(p, 1, 4);
  p += __shfl_down(p, 2, 4);
  if (q == 0) sSc[l] = p;
  __syncthreads();
  if (tid < 64) {
    float s = sSc[tid];
    float m = s;
    for (int off = 32; off; off >>= 1) m = fmaxf(m, __shfl_xor(m, off));
    float e = exp2f((s - m) * 1.4426950408889634f);
    float sum = e;
    for (int off = 32; off; off >>= 1) sum += __shfl_xor(sum, off);
    float a = e / sum;
    sAtt[tid] = a;
    out_att[(size_t)n * 4032 + tid * 63 + t] = a;
  }
  __syncthreads();
  const float* er = enc_hids + ((size_t)n * 64) * 1024 + tid * 4;
  float c0 = 0, c1 = 0, c2 = 0, c3 = 0;
  for (int l2 = 0; l2 < 64; ++l2) {
    floatx4 ev = *(const floatx4*)(er + (size_t)l2 * 1024);
    float a = sAtt[l2];
    c0 += a * ev[0]; c1 += a * ev[1]; c2 += a * ev[2]; c3 += a * ev[3];
  }
  ushort_t* cp = ctxbf + n * 1024 + tid * 4;
  cp[0] = f2bf(c0); cp[1] = f2bf(c1); cp[2] = f2bf(c2); cp[3] = f2bf(c3);
}

// ---------------------------------------------------------------------------
// GRU layer body (verbatim math from verified gru_k). vb in [0,128).
__device__ __forceinline__ void gru_body(int b, int tid,
    const ushort_t* __restrict__ Xs, const ushort_t* __restrict__ Wg,
    const float* __restrict__ gh, const float* __restrict__ hp,
    float* __restrict__ ho, ushort_t* __restrict__ hobf,
    const float* __restrict__ add, float* __restrict__ outh,
    ushort_t* sX16, float* sRed) {
  int wid = tid >> 6, lane = tid & 63;
  int mh = b & 1, g = b >> 1, j0 = g * 16;
  #pragma unroll
  for (int it = 0; it < 8; ++it) {
    int v = it * 256 + tid; int row = v >> 7, vc = v & 127;
    *(bhalf8*)(&sX16[row * 1032 + vc * 8]) = *(const bhalf8*)(Xs + (size_t)(mh * 16 + row) * 1024 + vc * 8);
  }
  __syncthreads();
  floatx4 a0 = {0,0,0,0}, a1 = {0,0,0,0}, a2 = {0,0,0,0};
  int klane = (lane >> 4) << 3;
  const ushort_t* Wr = Wg + (size_t)(j0 + (lane & 15)) * 1024;
  for (int kit = 0; kit < 8; ++kit) {
    int k = wid * 256 + kit * 32 + klane;
    bhalf8 a = *(const bhalf8*)(&sX16[(lane & 15) * 1032 + k]);
    a0 = __builtin_amdgcn_mfma_f32_16x16x32_bf16(a, *(const bhalf8*)(Wr + k), a0, 0, 0, 0);
    a1 = __builtin_amdgcn_mfma_f32_16x16x32_bf16(a, *(const bhalf8*)(Wr + 1048576 + k), a1, 0, 0, 0);
    a2 = __builtin_amdgcn_mfma_f32_16x16x32_bf16(a, *(const bhalf8*)(Wr + 2097152 + k), a2, 0, 0, 0);
  }
  if (wid) {
    ((floatx4*)sRed)[((wid - 1) * 3 + 0) * 64 + lane] = a0;
    ((floatx4*)sRed)[((wid - 1) * 3 + 1) * 64 + lane] = a1;
    ((floatx4*)sRed)[((wid - 1) * 3 + 2) * 64 + lane] = a2;
  }
  __syncthreads();
  if (wid == 0) {
    #pragma unroll
    for (int w = 0; w < 3; ++w) {
      a0 += ((floatx4*)sRed)[(w * 3 + 0) * 64 + lane];
      a1 += ((floatx4*)sRed)[(w * 3 + 1) * 64 + lane];
      a2 += ((floatx4*)sRed)[(w * 3 + 2) * 64 + lane];
    }
    int col = j0 + (lane & 15), r0 = (lane >> 4) << 2;
    #pragma unroll
    for (int i = 0; i < 4; ++i) {
      int n = mh * 16 + r0 + i;
      float ir  = a0[i] + add[col];
      float iz  = a1[i] + add[col + 1024];
      float inn = a2[i] + add[col + 2048];
      int gb = n * 3072 + col;
      float r = sigm_f(ir + gh[gb]);
      float z = sigm_f(iz + gh[gb + 1024]);
      float nn = tanh_f(inn + r * gh[gb + 2048]);
      float h = (1.f - z) * nn + z * hp[n * 1024 + col];
      ho[n * 1024 + col] = h;
      hobf[n * 1024 + col] = f2bf(h);
      if (outh) outh[(size_t)n * 64512 + col] = h;
    }
  }
}

// ---------------------------------------------------------------------------
// Persistent cooperative loop: all 63 steps, 5 phases/step with grid barriers.
//   P1: dprj = h2 @ Wad^T                  (vb 0..31)
//   P2: att (vb 0..31)  ||  gh1 (32..127)  ||  gh2 (128..223)
//   P3: mctx = ctx @ Wctx^T + membp[t]     (vb 0..31)
//   P4: gru layer 0   P5: gru layer 1      (vb 0..127)
// Tail: copy h1/h2 -> out_prev (vb 0..63).
__global__ __launch_bounds__(256, 1) void loop_k(
    const ushort_t* __restrict__ encp, const ushort_t* __restrict__ membp,
    const ushort_t* __restrict__ Wad, const ushort_t* __restrict__ Whh,
    const ushort_t* __restrict__ Wih, const ushort_t* __restrict__ Wctx,
    const float* __restrict__ bhh, const float* __restrict__ bih,
    const ushort_t* __restrict__ vattbf, const float* __restrict__ enc_hids,
    float* __restrict__ h1, float* __restrict__ h2,
    ushort_t* __restrict__ h1bf, ushort_t* __restrict__ h2bf,
    ushort_t* __restrict__ ctxbf, ushort_t* __restrict__ mctx,
    float* __restrict__ dprj, float* __restrict__ gh1, float* __restrict__ gh2,
    float* __restrict__ out_hid, float* __restrict__ out_att,
    float* __restrict__ out_prev) {
  cg::grid_group grid = cg::this_grid();
  __shared__ __align__(16) char smem[42240];
  ushort_t* sXk  = (ushort_t*)smem;            // 16896 B
  ushort_t* sBk  = (ushort_t*)(smem + 16896);  // 16896 B
  ushort_t* sX16 = (ushort_t*)smem;            // 33024 B (gru)
  float*    sRed = (float*)(smem + 33024);     // 9216 B  (gru)
  float*    sSc  = (float*)smem;               // 256 B   (att)
  float*    sAtt = (float*)(smem + 256);       // 256 B   (att)

  int b = blockIdx.x, tid = threadIdx.x;
  int wid = tid >> 6, lane = tid & 63;
  int nt = wid & 1, mt = wid >> 1;

  for (int t = 0; t < T_STEPS; ++t) {
    // ---- P1: dprj (32 vblocks) ----
    if (b < 32) {
      floatx4 acc = tile_gemm32(h2bf, Wad + (size_t)(b * 32) * 1024, sXk, sBk, tid);
      int colw = b * 32 + nt * 16 + (lane & 15);
      int rl = (lane >> 4) << 2;
      #pragma unroll
      for (int i = 0; i < 4; ++i)
        dprj[(size_t)(mt * 16 + rl + i) * 1024 + colw] = acc[i];
    }
    grid.sync();

    // ---- P2: att || gh1 || gh2 ----
    if (b < 32) {
      att_body(t, b, tid, encp, dprj, vattbf, enc_hids, ctxbf, out_att, sSc, sAtt);
    } else {
      const ushort_t* Xs; const ushort_t* Wp; const float* bp; float* Co; int colbase;
      if (b < 128) { Xs = h1bf; Wp = Whh;           bp = bhh;        Co = gh1; colbase = (b - 32) * 32; }
      else         { Xs = h2bf; Wp = Whh + 3145728; bp = bhh + 3072; Co = gh2; colbase = (b - 128) * 32; }
      floatx4 acc = tile_gemm32(Xs, Wp + (size_t)colbase * 1024, sXk, sBk, tid);
      int colw = colbase + nt * 16 + (lane & 15);
      float bv = bp[colw];
      int rl = (lane >> 4) << 2;
      #pragma unroll
      for (int i = 0; i < 4; ++i)
        Co[(size_t)(mt * 16 + rl + i) * 3072 + colw] = acc[i] + bv;
    }
    grid.sync();

    // ---- P3: mctx (32 vblocks) ----
    if (b < 32) {
      const ushort_t* mp = membp + (size_t)t * 32768;
      floatx4 acc = tile_gemm32(ctxbf, Wctx + (size_t)(b * 32) * 1024, sXk, sBk, tid);
      int colw = b * 32 + nt * 16 + (lane & 15);
      int rl = (lane >> 4) << 2;
      #pragma unroll
      for (int i = 0; i < 4; ++i) {
        int row = mt * 16 + rl + i;
        mctx[(size_t)row * 1024 + colw] = f2bf(acc[i] + bf2f(mp[(size_t)row * 1024 + colw]));
      }
    }
    grid.sync();

    // ---- P4: gru layer 0 ----
    if (b < 128)
      gru_body(b, tid, mctx, Wih, gh1, h1, h1, h1bf, bih, (float*)nullptr, sX16, sRed);
    grid.sync();

    // ---- P5: gru layer 1 ----
    if (b < 128)
      gru_body(b, tid, h1bf, Wih + 3145728, gh2, h2, h2, h2bf, bih + 3072,
               out_hid + (size_t)t * 1024, sX16, sRed);
    grid.sync();
  }

  // ---- tail: dec_prev output ----
  if (b < 64) {
    int l = b >> 5, n = b & 31;
    const float* src = l ? h2 : h1;
    float* dst = out_prev + (size_t)l * 32768 + n * 1024;
    for (int c = tid; c < 1024; c += 256) dst[c] = src[n * 1024 + c];
  }
}

// ---------------------------------------------------------------------------
// Fallback wrappers (verified 5-launch structure) in case cooperative launch
// is rejected (e.g. by graph capture). Same device bodies.
// ---------------------------------------------------------------------------
__global__ __launch_bounds__(256) void stage0_w(
    const ushort_t* __restrict__ h1bf, const ushort_t* __restrict__ h2bf,
    const ushort_t* __restrict__ Wad, const ushort_t* __restrict__ Whh,
    const float* __restrict__ bhh,
    float* __restrict__ dprj, float* __restrict__ gh1, float* __restrict__ gh2) {
  __shared__ __align__(16) ushort_t sXk[32 * 264];
  __shared__ __align__(16) ushort_t sBk[32 * 264];
  int b = blockIdx.x, tid = threadIdx.x;
  int wid = tid >> 6, lane = tid & 63;
  int nt = wid & 1, mt = wid >> 1;
  const ushort_t *Xs, *Wp; const float* bp; float* Co; int ldc, colbase;
  if (b < 32)       { Xs = h2bf; Wp = Wad;           bp = nullptr;    Co = dprj; ldc = 1024; colbase = b * 32; }
  else if (b < 128) { Xs = h1bf; Wp = Whh;           bp = bhh;        Co = gh1;  ldc = 3072; colbase = (b - 32) * 32; }
  else              { Xs = h2bf; Wp = Whh + 3145728; bp = bhh + 3072; Co = gh2;  ldc = 3072; colbase = (b - 128) * 32; }
  floatx4 acc = tile_gemm32(Xs, Wp + (size_t)colbase * 1024, sXk, sBk, tid);
  int colw = colbase + nt * 16 + (lane & 15);
  float bv = bp ? bp[colw] : 0.f;
  int rl = (lane >> 4) << 2;
  #pragma unroll
  for (int i = 0; i < 4; ++i)
    Co[(size_t)(mt * 16 + rl + i) * ldc + colw] = acc[i] + bv;
}

__global__ __launch_bounds__(256) void att_w(int t,
    const ushort_t* __restrict__ encp, const float* __restrict__ dprj,
    const ushort_t* __restrict__ vattbf, const float* __restrict__ enc_hids,
    ushort_t* __restrict__ ctxbf, float* __restrict__ out_att) {
  __shared__ float sSc[64];
  __shared__ float sAtt[64];
  att_body(t, blockIdx.x, threadIdx.x, encp, dprj, vattbf, enc_hids, ctxbf, out_att, sSc, sAtt);
}

__global__ __launch_bounds__(256) void mctx_w(
    const ushort_t* __restrict__ ctxbf, const ushort_t* __restrict__ Wctx,
    const ushort_t* __restrict__ membp_t, ushort_t* __restrict__ mctx) {
  __shared__ __align__(16) ushort_t sXk[32 * 264];
  __shared__ __align__(16) ushort_t sBk[32 * 264];
  int b = blockIdx.x, tid = threadIdx.x;
  int wid = tid >> 6, lane = tid & 63;
  int nt = wid & 1, mt = wid >> 1;
  floatx4 acc = tile_gemm32(ctxbf, Wctx + (size_t)(b * 32) * 1024, sXk, sBk, tid);
  int colw = b * 32 + nt * 16 + (lane & 15);
  int rl = (lane >> 4) << 2;
  #pragma unroll
  for (int i = 0; i < 4; ++i) {
    int row = mt * 16 + rl + i;
    mctx[(size_t)row * 1024 + colw] = f2bf(acc[i] + bf2f(membp_t[(size_t)row * 1024 + colw]));
  }
}

__global__ __launch_bounds__(256) void gru_w(
    const ushort_t* __restrict__ Xs, const ushort_t* __restrict__ Wg,
    const float* __restrict__ gh, const float* __restrict__ hp,
    float* __restrict__ ho, ushort_t* __restrict__ hobf,
    const float* __restrict__ add, float* __restrict__ outh) {
  __shared__ __align__(16) ushort_t sX16[16 * 1032];
  __shared__ __align__(16) float sRed[2304];
  gru_body(blockIdx.x, threadIdx.x, Xs, Wg, gh, hp, ho, hobf, add, outh, sX16, sRed);
}

__global__ __launch_bounds__(256) void final_w(const float* __restrict__ h1,
                                               const float* __restrict__ h2,
                                               float* __restrict__ outp) {
  int b = blockIdx.x; int l = b >> 5, n = b & 31;
  const float* src = l ? h2 : h1;
  float* dst = outp + (size_t)l * 32768 + n * 1024;
  for (int c = threadIdx.x; c < 1024; c += 256) dst[c] = src[n * 1024 + c];
}

// ---------------------------------------------------------------------------
extern "C" void kernel_launch(void* const* d_in, const int* in_sizes, int n_in,
                              void* d_out, int out_size, void* d_ws, size_t ws_size,
                              hipStream_t stream) {
  const int*   input_ids = (const int*)d_in[0];
  const float* dec_init  = (const float*)d_in[1];
  const float* enc_hids  = (const float*)d_in[2];
  const float* emb_table = (const float*)d_in[3];
  const float* W_in      = (const float*)d_in[4];
  const float* b_in      = (const float*)d_in[5];
  const float* W_ctx     = (const float*)d_in[6];
  const float* b_ctx     = (const float*)d_in[7];
  const float* W_att_dec = (const float*)d_in[8];
  const float* W_att_enc = (const float*)d_in[9];
  const float* v_att     = (const float*)d_in[10];
  const float* W_ih      = (const float*)d_in[11];
  const float* W_hh      = (const float*)d_in[12];
  const float* b_ih      = (const float*)d_in[13];
  const float* b_hh      = (const float*)d_in[14];
  (void)in_sizes; (void)n_in; (void)out_size;

  // ---- workspace layout (bytes), total 39,133,184 (~37.3 MB) ----
  const size_t WS_NEEDED = 39133184;
  if (ws_size < WS_NEEDED) return;
  char* ws = (char*)d_ws;
  float*    h1      = (float*)   (ws + 0);         // 131072
  float*    h2      = (float*)   (ws + 131072);    // 131072
  ushort_t* h1bf    = (ushort_t*)(ws + 262144);    // 65536
  ushort_t* h2bf    = (ushort_t*)(ws + 327680);    // 65536
  ushort_t* ctxbf   = (ushort_t*)(ws + 393216);    // 65536
  ushort_t* mctx    = (ushort_t*)(ws + 458752);    // 65536
  float*    dprj    = (float*)   (ws + 524288);    // 131072
  float*    gh1     = (float*)   (ws + 655360);    // 393216
  float*    gh2     = (float*)   (ws + 1048576);   // 393216
  float*    bsum    = (float*)   (ws + 1441792);   // 4096
  ushort_t* vattbf  = (ushort_t*)(ws + 1445888);   // 2048 (+2048 pad)
  ushort_t* encp    = (ushort_t*)(ws + 1449984);   // 4194304  (2048x1024)
  ushort_t* membp   = (ushort_t*)(ws + 5644288);   // 4128768  (2016x1024)
  ushort_t* Whh_bf  = (ushort_t*)(ws + 9773056);   // 12582912 (2x3072x1024)
  ushort_t* Wih_bf  = (ushort_t*)(ws + 22355968);  // 12582912 (2x3072x1024)
  ushort_t* Wad_bf  = (ushort_t*)(ws + 34938880);  // 2097152  (1024x1024)
  ushort_t* Wctx_bf = (ushort_t*)(ws + 37036032);  // 2097152  (1024x1024)

  // Precompute scratch aliased inside the Whh_bf region (written before Whh conv):
  ushort_t* encXbf  = (ushort_t*)(ws + 9773056);   // 4194304  (2048x1024 bf16)
  ushort_t* membXbf = (ushort_t*)(ws + 13967360);  // 4194304  (2048x1024 bf16, padded)
  ushort_t* Waebf   = (ushort_t*)(ws + 18161664);  // 2097152
  ushort_t* Winbf   = (ushort_t*)(ws + 20258816);  // 2097152  (ends at 22355968)

  float* out_hid  = (float*)d_out;            // (32, 63, 1024)
  float* out_att  = out_hid + 2064384;        // (32, 64, 63)
  float* out_prev = out_att + 129024;         // (2, 32, 1024)

  // -------- precompute (6 launches) --------
  bsum_k<<<dim3(4), dim3(256), 0, stream>>>(b_in, b_ctx, v_att, bsum, vattbf);
  init_k<<<dim3(256), dim3(256), 0, stream>>>(dec_init, h1, h2, h1bf, h2bf);
  // one fused conversion for all pre-GEMM operands + loop weights not in scratch:
  // enc_hids(524288q), W_att_enc(262144q), W_in(262144q), W_att_dec(262144q), W_ctx(262144q)
  conv5_k<<<dim3(6144), dim3(256), 0, stream>>>(
      enc_hids, encXbf, 524288,
      W_att_enc, Waebf, 262144,
      W_in, Winbf, 262144,
      W_att_dec, Wad_bf, 262144,
      W_ctx, Wctx_bf, 262144);
  gather_emb_k<<<dim3(2048), dim3(256), 0, stream>>>(input_ids, emb_table, membXbf);
  // encp = enc_hids @ Wae^T ; membp = emb @ W_in^T + bsum (one fused MFMA launch)
  gemm_pre2_k<<<dim3(4096), dim3(256), 0, stream>>>(encXbf, Waebf, membXbf, Winbf,
                                                    bsum, encp, membp);
  // recurrent-loop weights (overwrites the scratch region): Whh + Wih fused.
  conv5_k<<<dim3(12288), dim3(256), 0, stream>>>(
      W_hh, Whh_bf, 1572864,
      W_ih, Wih_bf, 1572864,
      (const float*)nullptr, (ushort_t*)nullptr, 0,
      (const float*)nullptr, (ushort_t*)nullptr, 0,
      (const float*)nullptr, (ushort_t*)nullptr, 0);

  // -------- persistent cooperative loop (1 dispatch, 63 steps) --------
  const ushort_t* a_encp = encp;  const ushort_t* a_membp = membp;
  const ushort_t* a_wad  = Wad_bf; const ushort_t* a_whh  = Whh_bf;
  const ushort_t* a_wih  = Wih_bf; const ushort_t* a_wctx = Wctx_bf;
  const float* a_bhh = b_hh; const float* a_bih = b_ih;
  const ushort_t* a_vatt = vattbf; const float* a_enc = enc_hids;
  float* a_h1 = h1; float* a_h2 = h2;
  ushort_t* a_h1bf = h1bf; ushort_t* a_h2bf = h2bf;
  ushort_t* a_ctx = ctxbf; ushort_t* a_mctx = mctx;
  float* a_dprj = dprj; float* a_gh1 = gh1; float* a_gh2 = gh2;
  float* a_oh = out_hid; float* a_oa = out_att; float* a_op = out_prev;
  void* args[] = { &a_encp, &a_membp, &a_wad, &a_whh, &a_wih, &a_wctx,
                   &a_bhh, &a_bih, &a_vatt, &a_enc,
                   &a_h1, &a_h2, &a_h1bf, &a_h2bf, &a_ctx, &a_mctx,
                   &a_dprj, &a_gh1, &a_gh2, &a_oh, &a_oa, &a_op };
  hipError_t ce = hipLaunchCooperativeKernel((void*)loop_k, dim3(224), dim3(256),
                                             args, 0, stream);
  if (ce != hipSuccess) {
    // Fallback: verified 5-launch-per-step pipeline.
    for (int t = 0; t < T_STEPS; ++t) {
      stage0_w<<<dim3(224), dim3(256), 0, stream>>>(h1bf, h2bf, Wad_bf, Whh_bf, b_hh,
                                                    dprj, gh1, gh2);
      att_w<<<dim3(32), dim3(256), 0, stream>>>(t, encp, dprj, vattbf, enc_hids,
                                                ctxbf, out_att);
      mctx_w<<<dim3(32), dim3(256), 0, stream>>>(ctxbf, Wctx_bf, membp + (size_t)t * 32768, mctx);
      gru_w<<<dim3(128), dim3(256), 0, stream>>>(mctx, Wih_bf, gh1, h1, h1, h1bf,
                                                 b_ih, (float*)nullptr);
      gru_w<<<dim3(128), dim3(256), 0, stream>>>(h1bf, Wih_bf + 3145728, gh2, h2, h2, h2bf,
                                                 b_ih + 3072, out_hid + (size_t)t * 1024);
    }
    final_w<<<dim3(64), dim3(256), 0, stream>>>(h1, h2, out_prev);
  }
}

// Round 17
// 10496.013 us; speedup vs baseline: 1.1996x; 1.1996x over previous
//
#include <hip/hip_runtime.h>
#include <cstddef>

typedef unsigned short ushort_t;
typedef __attribute__((ext_vector_type(8))) short bhalf8;
typedef __attribute__((ext_vector_type(4))) unsigned short ushort4v;
typedef __attribute__((ext_vector_type(4))) float floatx4;

#define T_STEPS 63

__device__ __forceinline__ float bf2f(unsigned short u) {
  union { unsigned int i; float f; } c; c.i = ((unsigned int)u) << 16; return c.f;
}
__device__ __forceinline__ unsigned short f2bf(float f) {
  union { float f; unsigned int i; } c; c.f = f;
  unsigned int x = c.i;
  return (unsigned short)((x + 0x7FFFu + ((x >> 16) & 1u)) >> 16);
}
__device__ __forceinline__ float tanh_f(float x) {
  float e = exp2f(x * 2.8853900817779268f);
  return 1.f - 2.f / (e + 1.f);
}
__device__ __forceinline__ float sigm_f(float x) {
  return 1.f / (1.f + exp2f(x * -1.4426950408889634f));
}

// ---------------------------------------------------------------------------
// Multi-segment fp32 -> bf16 conversion (up to 5 independent segments, quads).
__global__ __launch_bounds__(256) void conv5_k(
    const float* __restrict__ s0, ushort_t* __restrict__ d0, int n0,
    const float* __restrict__ s1, ushort_t* __restrict__ d1, int n1,
    const float* __restrict__ s2, ushort_t* __restrict__ d2, int n2,
    const float* __restrict__ s3, ushort_t* __restrict__ d3, int n3,
    const float* __restrict__ s4, ushort_t* __restrict__ d4, int n4) {
  int g = blockIdx.x * 256 + threadIdx.x;
  const float* s; ushort_t* d; int off;
  int e0 = n0, e1 = e0 + n1, e2 = e1 + n2, e3 = e2 + n3, e4 = e3 + n4;
  if      (g < e0) { s = s0; d = d0; off = g; }
  else if (g < e1) { s = s1; d = d1; off = g - e0; }
  else if (g < e2) { s = s2; d = d2; off = g - e1; }
  else if (g < e3) { s = s3; d = d3; off = g - e2; }
  else if (g < e4) { s = s4; d = d4; off = g - e3; }
  else return;
  floatx4 v = ((const floatx4*)s)[off];
  ushort4v o;
  o[0] = f2bf(v[0]); o[1] = f2bf(v[1]); o[2] = f2bf(v[2]); o[3] = f2bf(v[3]);
  ((ushort4v*)d)[off] = o;
}

// ---------------------------------------------------------------------------
// bsum[i] = b_in[i] + b_ctx[i] (f32); vattbf[i] = bf16(v_att[i]).
__global__ __launch_bounds__(256) void bsum_k(const float* __restrict__ b_in,
    const float* __restrict__ b_ctx, const float* __restrict__ v_att,
    float* __restrict__ bsum, ushort_t* __restrict__ vattbf) {
  int i = blockIdx.x * 256 + threadIdx.x;
  if (i < 1024) {
    bsum[i] = b_in[i] + b_ctx[i];
    vattbf[i] = f2bf(v_att[i]);
  }
}

// ---------------------------------------------------------------------------
// init h1/h2 (fp32 + bf16 mirror) from dec_init (NL,N,H) fp32. 65536 threads.
__global__ __launch_bounds__(256) void init_k(const float* __restrict__ dec_init,
    float* __restrict__ h1, float* __restrict__ h2,
    ushort_t* __restrict__ h1bf, ushort_t* __restrict__ h2bf) {
  int g = blockIdx.x * 256 + threadIdx.x;
  int l = g >> 15, idx = g & 32767;
  float f = dec_init[g];
  if (l == 0) { h1[idx] = f; h1bf[idx] = f2bf(f); }
  else        { h2[idx] = f; h2bf[idx] = f2bf(f); }
}

// ---------------------------------------------------------------------------
// Gather decoder-input embedding rows to bf16, padded to 2048 rows with zeros.
__global__ __launch_bounds__(256) void gather_emb_k(const int* __restrict__ ids,
    const float* __restrict__ emb_table, ushort_t* __restrict__ Xg) {
  int g = blockIdx.x * 256 + threadIdx.x;   // 524288 quads
  int row = g >> 8, q = g & 255;
  ushort4v o;
  if (row < 2016) {
    int tt = row >> 5, n = row & 31;
    int eid = ids[n * 64 + tt];
    floatx4 v = *(const floatx4*)(emb_table + (size_t)eid * 1024 + q * 4);
    o[0] = f2bf(v[0]); o[1] = f2bf(v[1]); o[2] = f2bf(v[2]); o[3] = f2bf(v[3]);
  } else {
    o[0] = 0; o[1] = 0; o[2] = 0; o[3] = 0;
  }
  ((ushort4v*)Xg)[g] = o;
}

// ---------------------------------------------------------------------------
// Shared 32-row x 32-col x K=1024 bf16 MFMA tile (verified structure).
__device__ __forceinline__ floatx4 tile_gemm32(
    const ushort_t* __restrict__ Xs, const ushort_t* __restrict__ Wp,
    ushort_t* sXk, ushort_t* sBk, int tid) {
  int wid = tid >> 6, lane = tid & 63;
  int klane = (lane >> 4) << 3;
  int nt = wid & 1, mt = wid >> 1;
  floatx4 acc = {0, 0, 0, 0};
  for (int kp = 0; kp < 4; ++kp) {
    __syncthreads();
    #pragma unroll
    for (int it = 0; it < 4; ++it) {
      int v = it * 256 + tid; int row = v >> 5, vc = v & 31;
      *(bhalf8*)(&sXk[row * 264 + vc * 8]) = *(const bhalf8*)(Xs + (size_t)row * 1024 + kp * 256 + vc * 8);
      *(bhalf8*)(&sBk[row * 264 + vc * 8]) = *(const bhalf8*)(Wp + (size_t)row * 1024 + kp * 256 + vc * 8);
    }
    __syncthreads();
    #pragma unroll
    for (int kit = 0; kit < 8; ++kit) {
      int k = kit * 32 + klane;
      bhalf8 a  = *(const bhalf8*)(&sXk[(mt * 16 + (lane & 15)) * 264 + k]);
      bhalf8 bf = *(const bhalf8*)(&sBk[(nt * 16 + (lane & 15)) * 264 + k]);
      acc = __builtin_amdgcn_mfma_f32_16x16x32_bf16(a, bf, acc, 0, 0, 0);
    }
  }
  return acc;
}

// ---------------------------------------------------------------------------
// Precompute GEMM body (verified round 4).
__device__ __forceinline__ void gemm_pre_body(int b, int tid,
    const ushort_t* __restrict__ Xbf, const ushort_t* __restrict__ Wbf,
    const float* __restrict__ bias, ushort_t* __restrict__ outp, int R,
    ushort_t* sXk, ushort_t* sBk) {
  int rb = b >> 5, cb = b & 31;
  int r0 = rb << 5, c0 = cb << 5;
  floatx4 acc = tile_gemm32(Xbf + (size_t)r0 * 1024, Wbf + (size_t)c0 * 1024, sXk, sBk, tid);
  int wid = tid >> 6, lane = tid & 63;
  int nt = wid & 1, mt = wid >> 1;
  int colw = c0 + nt * 16 + (lane & 15);
  float bv = bias ? bias[colw] : 0.f;
  int rl = (lane >> 4) << 2;
  #pragma unroll
  for (int i = 0; i < 4; ++i) {
    int row = r0 + mt * 16 + rl + i;
    if (row < R) outp[(size_t)row * 1024 + colw] = f2bf(acc[i] + bv);
  }
}

__global__ __launch_bounds__(256) void gemm_pre2_k(
    const ushort_t* __restrict__ encX, const ushort_t* __restrict__ Wae,
    const ushort_t* __restrict__ membX, const ushort_t* __restrict__ Win,
    const float* __restrict__ bsum,
    ushort_t* __restrict__ encp, ushort_t* __restrict__ membp) {
  __shared__ __align__(16) ushort_t sXk[32 * 264];
  __shared__ __align__(16) ushort_t sBk[32 * 264];
  int b = blockIdx.x, tid = threadIdx.x;
  if (b < 2048)
    gemm_pre_body(b, tid, encX, Wae, (const float*)nullptr, encp, 2048, sXk, sBk);
  else
    gemm_pre_body(b - 2048, tid, membX, Win, bsum, membp, 2016, sXk, sBk);
}

// ---------------------------------------------------------------------------
// L1: fused per-step kernel, 224 blocks.
//   b in [0,32):   full attention for batch n=b:
//                  dprj matvec (h2 row) -> score -> softmax -> ctx -> mctx matvec
//   b in [32,128): gh1 = h1 @ Whh0^T + bhh0   (verified MFMA tile)
//   b in [128,224):gh2 = h2 @ Whh1^T + bhh1
// All inputs are step-(t-1) state => safe concurrency.
__global__ __launch_bounds__(256) void fused1_k(int t,
    const ushort_t* __restrict__ h1bf, const ushort_t* __restrict__ h2bf,
    const ushort_t* __restrict__ Wad, const ushort_t* __restrict__ Whh,
    const float* __restrict__ bhh, const ushort_t* __restrict__ Wctx,
    const ushort_t* __restrict__ encp, const ushort_t* __restrict__ vattbf,
    const float* __restrict__ enc_hids, const ushort_t* __restrict__ membp_t,
    float* __restrict__ gh1, float* __restrict__ gh2,
    ushort_t* __restrict__ mctx, float* __restrict__ out_att) {
  __shared__ __align__(16) char smem[33792];
  int b = blockIdx.x, tid = threadIdx.x;

  if (b >= 32) {
    // ---- gh GEMM path (verbatim stage0 structure) ----
    ushort_t* sXk = (ushort_t*)smem;
    ushort_t* sBk = (ushort_t*)(smem + 16896);
    int wid = tid >> 6, lane = tid & 63;
    int nt = wid & 1, mt = wid >> 1;
    const ushort_t *Xs, *Wp; const float* bp; float* Co; int colbase;
    if (b < 128) { Xs = h1bf; Wp = Whh;           bp = bhh;        Co = gh1; colbase = (b - 32) * 32; }
    else         { Xs = h2bf; Wp = Whh + 3145728; bp = bhh + 3072; Co = gh2; colbase = (b - 128) * 32; }
    floatx4 acc = tile_gemm32(Xs, Wp + (size_t)colbase * 1024, sXk, sBk, tid);
    int colw = colbase + nt * 16 + (lane & 15);
    float bv = bp[colw];
    int rl = (lane >> 4) << 2;
    #pragma unroll
    for (int i = 0; i < 4; ++i)
      Co[(size_t)(mt * 16 + rl + i) * 3072 + colw] = acc[i] + bv;
    return;
  }

  // ---- attention path, n = b ----
  float* sIn  = (float*)smem;            // 4 KB: h2 (f32), later ctx (f32)
  float* sDp  = (float*)(smem + 4096);   // 4 KB: dprj row
  float* sSc  = (float*)(smem + 8192);   // 256 B
  float* sAtt = (float*)(smem + 8448);   // 256 B
  int n = b;

  // stage h2 row n -> f32 LDS
  {
    ushort4v hv = ((const ushort4v*)(h2bf + (size_t)n * 1024))[tid];
    sIn[tid * 4 + 0] = bf2f(hv[0]); sIn[tid * 4 + 1] = bf2f(hv[1]);
    sIn[tid * 4 + 2] = bf2f(hv[2]); sIn[tid * 4 + 3] = bf2f(hv[3]);
  }
  __syncthreads();

  // dprj[n,c] = sum_k h2[k] * Wad[c,k]  (4 passes, col c = tid + 256*pp)
  for (int pp = 0; pp < 4; ++pp) {
    int c = tid + pp * 256;
    const ushort_t* w = Wad + (size_t)c * 1024;
    float a = 0.f;
    for (int k = 0; k < 1024; k += 8) {
      bhalf8 wv = *(const bhalf8*)(w + k);
      floatx4 cA = *(const floatx4*)(&sIn[k]);
      floatx4 cB = *(const floatx4*)(&sIn[k + 4]);
      a += cA[0] * bf2f((unsigned short)wv[0]) + cA[1] * bf2f((unsigned short)wv[1])
         + cA[2] * bf2f((unsigned short)wv[2]) + cA[3] * bf2f((unsigned short)wv[3])
         + cB[0] * bf2f((unsigned short)wv[4]) + cB[1] * bf2f((unsigned short)wv[5])
         + cB[2] * bf2f((unsigned short)wv[6]) + cB[3] * bf2f((unsigned short)wv[7]);
    }
    sDp[c] = a;
  }
  __syncthreads();

  // score: l = tid>>2 (enc position), q = tid&3 (k-quarter)
  {
    int l = tid >> 2, q = tid & 3;
    const ushort_t* ep = encp + ((size_t)(n * 64 + l)) * 1024 + q * 256;
    const float* dpL = sDp + q * 256;
    float sc = 0.f;
    for (int it = 0; it < 32; ++it) {
      bhalf8 E = *(const bhalf8*)(ep + it * 8);
      bhalf8 V = *(const bhalf8*)(vattbf + q * 256 + it * 8);
      #pragma unroll
      for (int r = 0; r < 8; ++r)
        sc += tanh_f(bf2f((unsigned short)E[r]) + dpL[it * 8 + r]) * bf2f((unsigned short)V[r]);
    }
    sc += __shfl_down(sc, 1, 4);
    sc += __shfl_down(sc, 2, 4);
    if (q == 0) sSc[l] = sc;
  }
  __syncthreads();
  if (tid < 64) {
    float s = sSc[tid];
    float m = s;
    for (int off = 32; off; off >>= 1) m = fmaxf(m, __shfl_xor(m, off));
    float e = exp2f((s - m) * 1.4426950408889634f);
    float sum = e;
    for (int off = 32; off; off >>= 1) sum += __shfl_xor(sum, off);
    float a = e / sum;
    sAtt[tid] = a;
    out_att[(size_t)n * 4032 + tid * 63 + t] = a;
  }
  __syncthreads();

  // ctx (fp32) -> sIn (h2 content dead)
  {
    const float* er = enc_hids + ((size_t)n * 64) * 1024 + tid * 4;
    float c0 = 0, c1 = 0, c2 = 0, c3 = 0;
    for (int l2 = 0; l2 < 64; ++l2) {
      floatx4 ev = *(const floatx4*)(er + (size_t)l2 * 1024);
      float a = sAtt[l2];
      c0 += a * ev[0]; c1 += a * ev[1]; c2 += a * ev[2]; c3 += a * ev[3];
    }
    sIn[tid * 4 + 0] = c0; sIn[tid * 4 + 1] = c1;
    sIn[tid * 4 + 2] = c2; sIn[tid * 4 + 3] = c3;
  }
  __syncthreads();

  // mctx[n,c] = bf16( sum_k ctx[k]*Wctx[c,k] + membp[t,n,c] )
  for (int pp = 0; pp < 4; ++pp) {
    int c = tid + pp * 256;
    const ushort_t* w = Wctx + (size_t)c * 1024;
    float a = 0.f;
    for (int k = 0; k < 1024; k += 8) {
      bhalf8 wv = *(const bhalf8*)(w + k);
      floatx4 cA = *(const floatx4*)(&sIn[k]);
      floatx4 cB = *(const floatx4*)(&sIn[k + 4]);
      a += cA[0] * bf2f((unsigned short)wv[0]) + cA[1] * bf2f((unsigned short)wv[1])
         + cA[2] * bf2f((unsigned short)wv[2]) + cA[3] * bf2f((unsigned short)wv[3])
         + cB[0] * bf2f((unsigned short)wv[4]) + cB[1] * bf2f((unsigned short)wv[5])
         + cB[2] * bf2f((unsigned short)wv[6]) + cB[3] * bf2f((unsigned short)wv[7]);
    }
    mctx[(size_t)n * 1024 + c] = f2bf(a + bf2f(membp_t[(size_t)n * 1024 + c]));
  }
}

// ---------------------------------------------------------------------------
// GRU layer body (verified). vb in [0,128).
__device__ __forceinline__ void gru_body(int b, int tid,
    const ushort_t* __restrict__ Xs, const ushort_t* __restrict__ Wg,
    const float* __restrict__ gh, const float* __restrict__ hp,
    float* __restrict__ ho, ushort_t* __restrict__ hobf,
    const float* __restrict__ add, float* __restrict__ outh,
    ushort_t* sX16, float* sRed) {
  int wid = tid >> 6, lane = tid & 63;
  int mh = b & 1, g = b >> 1, j0 = g * 16;
  #pragma unroll
  for (int it = 0; it < 8; ++it) {
    int v = it * 256 + tid; int row = v >> 7, vc = v & 127;
    *(bhalf8*)(&sX16[row * 1032 + vc * 8]) = *(const bhalf8*)(Xs + (size_t)(mh * 16 + row) * 1024 + vc * 8);
  }
  __syncthreads();
  floatx4 a0 = {0,0,0,0}, a1 = {0,0,0,0}, a2 = {0,0,0,0};
  int klane = (lane >> 4) << 3;
  const ushort_t* Wr = Wg + (size_t)(j0 + (lane & 15)) * 1024;
  for (int kit = 0; kit < 8; ++kit) {
    int k = wid * 256 + kit * 32 + klane;
    bhalf8 a = *(const bhalf8*)(&sX16[(lane & 15) * 1032 + k]);
    a0 = __builtin_amdgcn_mfma_f32_16x16x32_bf16(a, *(const bhalf8*)(Wr + k), a0, 0, 0, 0);
    a1 = __builtin_amdgcn_mfma_f32_16x16x32_bf16(a, *(const bhalf8*)(Wr + 1048576 + k), a1, 0, 0, 0);
    a2 = __builtin_amdgcn_mfma_f32_16x16x32_bf16(a, *(const bhalf8*)(Wr + 2097152 + k), a2, 0, 0, 0);
  }
  if (wid) {
    ((floatx4*)sRed)[((wid - 1) * 3 + 0) * 64 + lane] = a0;
    ((floatx4*)sRed)[((wid - 1) * 3 + 1) * 64 + lane] = a1;
    ((floatx4*)sRed)[((wid - 1) * 3 + 2) * 64 + lane] = a2;
  }
  __syncthreads();
  if (wid == 0) {
    #pragma unroll
    for (int w = 0; w < 3; ++w) {
      a0 += ((floatx4*)sRed)[(w * 3 + 0) * 64 + lane];
      a1 += ((floatx4*)sRed)[(w * 3 + 1) * 64 + lane];
      a2 += ((floatx4*)sRed)[(w * 3 + 2) * 64 + lane];
    }
    int col = j0 + (lane & 15), r0 = (lane >> 4) << 2;
    #pragma unroll
    for (int i = 0; i < 4; ++i) {
      int n = mh * 16 + r0 + i;
      float ir  = a0[i] + add[col];
      float iz  = a1[i] + add[col + 1024];
      float inn = a2[i] + add[col + 2048];
      int gb = n * 3072 + col;
      float r = sigm_f(ir + gh[gb]);
      float z = sigm_f(iz + gh[gb + 1024]);
      float nn = tanh_f(inn + r * gh[gb + 2048]);
      float h = (1.f - z) * nn + z * hp[n * 1024 + col];
      ho[n * 1024 + col] = h;
      hobf[n * 1024 + col] = f2bf(h);
      if (outh) outh[(size_t)n * 64512 + col] = h;
    }
  }
}

__global__ __launch_bounds__(256) void gru_w(
    const ushort_t* __restrict__ Xs, const ushort_t* __restrict__ Wg,
    const float* __restrict__ gh, const float* __restrict__ hp,
    float* __restrict__ ho, ushort_t* __restrict__ hobf,
    const float* __restrict__ add, float* __restrict__ outh) {
  __shared__ __align__(16) ushort_t sX16[16 * 1032];
  __shared__ __align__(16) float sRed[2304];
  gru_body(blockIdx.x, threadIdx.x, Xs, Wg, gh, hp, ho, hobf, add, outh, sX16, sRed);
}

__global__ __launch_bounds__(256) void final_w(const float* __restrict__ h1,
                                               const float* __restrict__ h2,
                                               float* __restrict__ outp) {
  int b = blockIdx.x; int l = b >> 5, n = b & 31;
  const float* src = l ? h2 : h1;
  float* dst = outp + (size_t)l * 32768 + n * 1024;
  for (int c = threadIdx.x; c < 1024; c += 256) dst[c] = src[n * 1024 + c];
}

// ---------------------------------------------------------------------------
extern "C" void kernel_launch(void* const* d_in, const int* in_sizes, int n_in,
                              void* d_out, int out_size, void* d_ws, size_t ws_size,
                              hipStream_t stream) {
  const int*   input_ids = (const int*)d_in[0];
  const float* dec_init  = (const float*)d_in[1];
  const float* enc_hids  = (const float*)d_in[2];
  const float* emb_table = (const float*)d_in[3];
  const float* W_in      = (const float*)d_in[4];
  const float* b_in      = (const float*)d_in[5];
  const float* W_ctx     = (const float*)d_in[6];
  const float* b_ctx     = (const float*)d_in[7];
  const float* W_att_dec = (const float*)d_in[8];
  const float* W_att_enc = (const float*)d_in[9];
  const float* v_att     = (const float*)d_in[10];
  const float* W_ih      = (const float*)d_in[11];
  const float* W_hh      = (const float*)d_in[12];
  const float* b_ih      = (const float*)d_in[13];
  const float* b_hh      = (const float*)d_in[14];
  (void)in_sizes; (void)n_in; (void)out_size;

  // ---- workspace layout (bytes), total 39,133,184 (~37.3 MB) ----
  const size_t WS_NEEDED = 39133184;
  if (ws_size < WS_NEEDED) return;
  char* ws = (char*)d_ws;
  float*    h1      = (float*)   (ws + 0);         // 131072
  float*    h2      = (float*)   (ws + 131072);    // 131072
  ushort_t* h1bf    = (ushort_t*)(ws + 262144);    // 65536
  ushort_t* h2bf    = (ushort_t*)(ws + 327680);    // 65536
  ushort_t* mctx    = (ushort_t*)(ws + 458752);    // 65536
  float*    gh1     = (float*)   (ws + 655360);    // 393216
  float*    gh2     = (float*)   (ws + 1048576);   // 393216
  float*    bsum    = (float*)   (ws + 1441792);   // 4096
  ushort_t* vattbf  = (ushort_t*)(ws + 1445888);   // 2048 (+2048 pad)
  ushort_t* encp    = (ushort_t*)(ws + 1449984);   // 4194304  (2048x1024)
  ushort_t* membp   = (ushort_t*)(ws + 5644288);   // 4128768  (2016x1024)
  ushort_t* Whh_bf  = (ushort_t*)(ws + 9773056);   // 12582912 (2x3072x1024)
  ushort_t* Wih_bf  = (ushort_t*)(ws + 22355968);  // 12582912 (2x3072x1024)
  ushort_t* Wad_bf  = (ushort_t*)(ws + 34938880);  // 2097152  (1024x1024)
  ushort_t* Wctx_bf = (ushort_t*)(ws + 37036032);  // 2097152  (1024x1024)

  // Precompute scratch aliased inside the Whh_bf region (consumed before Whh conv):
  ushort_t* encXbf  = (ushort_t*)(ws + 9773056);   // 4194304  (2048x1024 bf16)
  ushort_t* membXbf = (ushort_t*)(ws + 13967360);  // 4194304  (2048x1024 bf16, padded)
  ushort_t* Waebf   = (ushort_t*)(ws + 18161664);  // 2097152
  ushort_t* Winbf   = (ushort_t*)(ws + 20258816);  // 2097152  (ends at 22355968)

  float* out_hid  = (float*)d_out;            // (32, 63, 1024)
  float* out_att  = out_hid + 2064384;        // (32, 64, 63)
  float* out_prev = out_att + 129024;         // (2, 32, 1024)

  // -------- precompute (6 launches, verified round 4) --------
  bsum_k<<<dim3(4), dim3(256), 0, stream>>>(b_in, b_ctx, v_att, bsum, vattbf);
  init_k<<<dim3(256), dim3(256), 0, stream>>>(dec_init, h1, h2, h1bf, h2bf);
  conv5_k<<<dim3(6144), dim3(256), 0, stream>>>(
      enc_hids, encXbf, 524288,
      W_att_enc, Waebf, 262144,
      W_in, Winbf, 262144,
      W_att_dec, Wad_bf, 262144,
      W_ctx, Wctx_bf, 262144);
  gather_emb_k<<<dim3(2048), dim3(256), 0, stream>>>(input_ids, emb_table, membXbf);
  gemm_pre2_k<<<dim3(4096), dim3(256), 0, stream>>>(encXbf, Waebf, membXbf, Winbf,
                                                    bsum, encp, membp);
  conv5_k<<<dim3(12288), dim3(256), 0, stream>>>(
      W_hh, Whh_bf, 1572864,
      W_ih, Wih_bf, 1572864,
      (const float*)nullptr, (ushort_t*)nullptr, 0,
      (const float*)nullptr, (ushort_t*)nullptr, 0,
      (const float*)nullptr, (ushort_t*)nullptr, 0);

  // -------- recurrent loop: 3 launches/step (L2 stays warm across launches) ----
  for (int t = 0; t < T_STEPS; ++t) {
    fused1_k<<<dim3(224), dim3(256), 0, stream>>>(t, h1bf, h2bf, Wad_bf, Whh_bf, b_hh,
                                                  Wctx_bf, encp, vattbf, enc_hids,
                                                  membp + (size_t)t * 32768,
                                                  gh1, gh2, mctx, out_att);
    gru_w<<<dim3(128), dim3(256), 0, stream>>>(mctx, Wih_bf, gh1, h1, h1, h1bf,
                                               b_ih, (float*)nullptr);
    gru_w<<<dim3(128), dim3(256), 0, stream>>>(h1bf, Wih_bf + 3145728, gh2, h2, h2, h2bf,
                                               b_ih + 3072, out_hid + (size_t)t * 1024);
  }
  final_w<<<dim3(64), dim3(256), 0, stream>>>(h1, h2, out_prev);
}